// Round 7
// baseline (347.371 us; speedup 1.0000x reference)
//
#include <hip/hip_runtime.h>
#include <hip/hip_cooperative_groups.h>
#include <cstddef>

namespace cg = cooperative_groups;

// Problem constants
#define BB   8
#define CC   64
#define H1   128
#define W1   128
#define HW1  (H1*W1)
#define HS   60
#define WS   60
#define HO   129
#define WO   129
#define NPIX (HS*WS)        // 3600
#define NCHUNK 15           // 60 rows = 15 chunks x 4 rows

// U: 36 planes of [BB][HW1], stored fp16
#define UPL  (BB*HW1)       // 131072 elements per t-plane

typedef _Float16 f16;

// ---------------------------------------------------------------------------
// Single cooperative kernel, 512 blocks x 256 threads, 4 phases:
//  A (blk<120): x2 inv-norm (in-LDS) + atomic-free patch-fold partials -> Spart
//  B (blk<72) : sum 15 chunk-partials -> S[b,c,36]
//  C (all)    : U[t][b][p] = inv1[b,p]*(1/3600)*sum_c x1[b,c,p]*S[b,c,t], fp16
//  D (all)    : out129 gather (36 shifted planes) + bilinear-antialias resize
__global__ __launch_bounds__(256) void k_all(const float* __restrict__ x1,
                                             const float* __restrict__ x2,
                                             float* __restrict__ Spart,
                                             float* __restrict__ S,
                                             f16* __restrict__ U,
                                             float* __restrict__ out) {
    cg::grid_group grid = cg::this_grid();
    __shared__ float lds[420];          // A: inv[240]; D: m[20*21]
    int blk = blockIdx.x;
    int tid = threadIdx.x;

    // ---------------- Phase A: x2 prep (120 blocks) ----------------
    if (blk < BB * NCHUNK) {
        int b = blk / NCHUNK, chunk = blk - b * NCHUNK;
        int px0 = chunk * 240;          // 4 source rows of 60

        if (tid < 240) {
            const float* p = x2 + (size_t)b * CC * NPIX + px0 + tid;
            float s = 0.f;
#pragma unroll
            for (int c = 0; c < CC; ++c) { float v = p[c * NPIX]; s += v * v; }
            lds[tid] = 1.0f / sqrtf(s);
        }
        __syncthreads();

        int c = tid >> 2, q = tid & 3;
        int row = chunk * 4 + q;        // global source row (hh)
        const float* px = x2 + ((size_t)b * CC + c) * NPIX + row * WS;
        const float* iv = lds + q * 60;
        float acc[6] = {0, 0, 0, 0, 0, 0};
#pragma unroll
        for (int i = 0; i < 60; ++i)
            acc[i % 6] += px[i] * iv[i];    // i%6 is the dx bin

        float* sb = Spart + (((size_t)b * CC + c) * NCHUNK + chunk) * 36;
        int r0 = row % 6;               // dy bin owned by this thread
#pragma unroll
        for (int j = 0; j < 6; ++j) sb[r0 * 6 + j] = acc[j];
        if (q < 2) {                    // zero the 2 dy bins absent in chunk
            int rm = (chunk * 4 + 4 + q) % 6;
#pragma unroll
            for (int j = 0; j < 6; ++j) sb[rm * 6 + j] = 0.f;
        }
    }
    grid.sync();

    // ---------------- Phase B: reduce Spart -> S (72 blocks) ----------------
    if (blk < 72) {
        int e = blk * 256 + tid;        // 18432 = BB*CC*36 exactly
        int bc = e / 36, bin = e - bc * 36;
        const float* sp = Spart + (size_t)bc * NCHUNK * 36 + bin;
        float s = 0.f;
#pragma unroll
        for (int k = 0; k < NCHUNK; ++k) s += sp[k * 36];
        S[e] = s;
    }
    grid.sync();

    // ---------------- Phase C: gemm -> U (all 512 blocks) ----------------
    {
        int b = blk >> 6;
        int p = (blk & 63) * 256 + tid;

        const float* xp = x1 + (size_t)b * CC * HW1 + p;
        const float* Sb = S + (size_t)b * (CC * 36);   // uniform base

        float acc[36];
#pragma unroll
        for (int t = 0; t < 36; ++t) acc[t] = 0.f;
        float s2 = 0.f;

        for (int cc = 0; cc < CC; cc += 8) {
            float v[8];
#pragma unroll
            for (int j = 0; j < 8; ++j) v[j] = xp[(size_t)(cc + j) * HW1];
#pragma unroll
            for (int j = 0; j < 8; ++j) {
                const float* sj = Sb + (cc + j) * 36;   // uniform -> s_load
                float vv = v[j];
                s2 += vv * vv;
#pragma unroll
                for (int t = 0; t < 36; ++t) acc[t] += vv * sj[t];
            }
        }

        float inv = (1.0f / 3600.0f) / sqrtf(s2);
        f16* up = U + (size_t)b * HW1 + p;
#pragma unroll
        for (int t = 0; t < 36; ++t) up[(size_t)t * UPL] = (f16)(acc[t] * inv);
    }
    grid.sync();

    // ---------------- Phase D: gather + resize (all 512 blocks) ----------------
    {
        float* m = lds;                 // 20x21
        int b    = blk >> 6;
        int tile = blk & 63;
        int oy0 = (tile >> 3) * 16, ox0 = (tile & 7) * 16;
        int ry0 = oy0 - 1, rx0 = ox0 - 1;

        const f16* Ub = U + (size_t)b * HW1;

        __syncthreads();                // protect lds reuse (phase A inv)
        for (int i = tid; i < 400; i += 256) {
            int ly = i / 20, lx = i - ly * 20;
            int jy = min(max(ry0 + ly, 0), 128);
            int jx = min(max(rx0 + lx, 0), 128);
            float s = 0.f;
#pragma unroll
            for (int t = 0; t < 36; ++t) {
                int dy = t / 6, dx = t - dy * 6;
                int py = jy - 3 + dy, px = jx - 3 + dx;
                if ((unsigned)py < 128u && (unsigned)px < 128u)
                    s += (float)Ub[(size_t)t * UPL + py * W1 + px];
            }
            m[ly * 21 + lx] = s;
        }
        __syncthreads();

        const float inv_scale = 129.0f / 128.0f;
        const float ksc       = 128.0f / 129.0f;

        int oy = oy0 + (tid >> 4);
        int ox = ox0 + (tid & 15);

        float sy = (oy + 0.5f) * inv_scale - 0.5f;
        float sx = (ox + 0.5f) * inv_scale - 0.5f;
        int fy = (int)floorf(sy);
        int fx = (int)floorf(sx);

        float wy[4], wx[4];
        float sumy = 0.f, sumx = 0.f;
#pragma unroll
        for (int k = 0; k < 4; ++k) {
            int jy = fy - 1 + k;
            float w = 0.f;
            if (jy >= 0 && jy < HO) w = fmaxf(0.f, 1.0f - fabsf(sy - (float)jy) * ksc);
            wy[k] = w; sumy += w;
            int jx = fx - 1 + k;
            float w2 = 0.f;
            if (jx >= 0 && jx < WO) w2 = fmaxf(0.f, 1.0f - fabsf(sx - (float)jx) * ksc);
            wx[k] = w2; sumx += w2;
        }

        float r = 0.f;
#pragma unroll
        for (int ky = 0; ky < 4; ++ky) {
            if (wy[ky] == 0.f) continue;
            int ly = fy - 1 + ky - ry0;
            float rowv = 0.f;
#pragma unroll
            for (int kx = 0; kx < 4; ++kx) {
                if (wx[kx] == 0.f) continue;
                int lx = fx - 1 + kx - rx0;
                rowv += wx[kx] * m[ly * 21 + lx];
            }
            r += wy[ky] * rowv;
        }

        out[(size_t)b * HW1 + oy * W1 + ox] = r / (sumy * sumx);
    }
}

// ---------------------------------------------------------------------------
extern "C" void kernel_launch(void* const* d_in, const int* in_sizes, int n_in,
                              void* d_out, int out_size, void* d_ws, size_t ws_size,
                              hipStream_t stream) {
    const float* x1 = (const float*)d_in[0];   // (8,64,128,128)
    const float* x2 = (const float*)d_in[1];   // (8,64,60,60)
    float* out = (float*)d_out;

    float* ws    = (float*)d_ws;
    float* Spart = ws;                         // 8*64*15*36 = 276480 floats
    float* S     = Spart + (size_t)BB * CC * NCHUNK * 36;  // 18432 floats
    f16*   U     = (f16*)(S + BB * CC * 36);   // 36*131072 halves (9.4 MB)

    void* args[] = {(void*)&x1, (void*)&x2, (void*)&Spart, (void*)&S,
                    (void*)&U, (void*)&out};
    hipLaunchCooperativeKernel((void*)k_all, dim3(512), dim3(256),
                               args, 0, stream);
}

// Round 8
// 132.784 us; speedup vs baseline: 2.6161x; 2.6161x over previous
//
#include <hip/hip_runtime.h>
#include <cstddef>

// Problem constants
#define BB   8
#define CC   64
#define H1   128
#define W1   128
#define HW1  (H1*W1)
#define HS   60
#define WS   60
#define HO   129
#define WO   129
#define NPIX (HS*WS)        // 3600
#define NCHUNK 15           // 60 rows = 15 chunks x 4 rows

// U: 36 planes of [BB][HW1], stored fp16
#define UPL  (BB*HW1)       // 131072 elements per t-plane

typedef _Float16 f16;

// ---------------------------------------------------------------------------
// x2 prep: per (b, 4-row chunk) block. Computes channel inv-norm for its 240
// pixels in LDS, then each thread owns one (channel, source-row) and writes
// exclusive partial bins -> Spart. Atomic-free (row%6 unique per thread).
__global__ __launch_bounds__(256) void k_prep(const float* __restrict__ x2,
                                              float* __restrict__ Spart) {
    __shared__ float inv[240];
    int tid = threadIdx.x;
    int b = blockIdx.x / NCHUNK, chunk = blockIdx.x - b * NCHUNK;
    int px0 = chunk * 240;          // 4 source rows of 60

    if (tid < 240) {
        const float* p = x2 + (size_t)b * CC * NPIX + px0 + tid;
        float s = 0.f;
#pragma unroll
        for (int c = 0; c < CC; ++c) { float v = p[c * NPIX]; s += v * v; }
        inv[tid] = 1.0f / sqrtf(s);
    }
    __syncthreads();

    int c = tid >> 2, q = tid & 3;
    int row = chunk * 4 + q;        // global source row (hh)
    const float* px = x2 + ((size_t)b * CC + c) * NPIX + row * WS;
    const float* iv = inv + q * 60;
    float acc[6] = {0, 0, 0, 0, 0, 0};
#pragma unroll
    for (int i = 0; i < 60; ++i)
        acc[i % 6] += px[i] * iv[i];    // i%6 is the dx bin

    float* sb = Spart + (((size_t)b * CC + c) * NCHUNK + chunk) * 36;
    int r0 = row % 6;               // dy bin owned by this thread
#pragma unroll
    for (int j = 0; j < 6; ++j) sb[r0 * 6 + j] = acc[j];
    if (q < 2) {                    // zero the 2 dy bins absent in this chunk
        int rm = (chunk * 4 + 4 + q) % 6;
#pragma unroll
        for (int j = 0; j < 6; ++j) sb[rm * 6 + j] = 0.f;
    }
}

// sum 15 chunk-partials -> S[b,c,36]  (18432 elements, L2-resident)
__global__ __launch_bounds__(256) void k_sum(const float* __restrict__ Spart,
                                             float* __restrict__ S) {
    int e = blockIdx.x * 256 + threadIdx.x;   // 72 blocks, exact
    int bc = e / 36, bin = e - bc * 36;
    const float* sp = Spart + (size_t)bc * NCHUNK * 36 + bin;
    float s = 0.f;
#pragma unroll
    for (int k = 0; k < NCHUNK; ++k) s += sp[k * 36];
    S[e] = s;
}

// ---------------------------------------------------------------------------
// U[t][b][p] = inv1[b,p] * (1/3600) * sum_c x1[b,c,p] * S[b,c,t]
// inv1 computed in the same pass (x1 read exactly once).
// S is block-uniform -> scalar-cache loads. U stored as fp16.
__global__ __launch_bounds__(256) void k_gemm(const float* __restrict__ x1,
                                              const float* __restrict__ S,
                                              f16* __restrict__ U) {
    int b = blockIdx.x >> 6;                    // 512 blocks: 8 b x 64 chunks
    int p = (blockIdx.x & 63) * 256 + threadIdx.x;

    const float* xp = x1 + (size_t)b * CC * HW1 + p;
    const float* Sb = S + (size_t)b * (CC * 36);   // uniform base

    float acc[36];
#pragma unroll
    for (int t = 0; t < 36; ++t) acc[t] = 0.f;
    float s2 = 0.f;

    for (int cc = 0; cc < CC; cc += 8) {
        float v[8];
#pragma unroll
        for (int j = 0; j < 8; ++j) v[j] = xp[(size_t)(cc + j) * HW1];
#pragma unroll
        for (int j = 0; j < 8; ++j) {
            const float* sj = Sb + (cc + j) * 36;   // uniform -> s_load
            float vv = v[j];
            s2 += vv * vv;
#pragma unroll
            for (int t = 0; t < 36; ++t) acc[t] += vv * sj[t];
        }
    }

    float inv = (1.0f / 3600.0f) / sqrtf(s2);
    f16* up = U + (size_t)b * HW1 + p;
#pragma unroll
    for (int t = 0; t < 36; ++t) up[(size_t)t * UPL] = (f16)(acc[t] * inv);
}

// ---------------------------------------------------------------------------
// Fused: out129 tile via 36-plane shifted gather of U (fp16), then bilinear
// antialias resize 129->128. One block per 16x16 output tile.
__global__ __launch_bounds__(256) void k_out(const f16* __restrict__ U,
                                             float* __restrict__ out) {
    __shared__ float m[20 * 21];
    int blk  = blockIdx.x;           // 8 b x 64 tiles
    int b    = blk >> 6;
    int tile = blk & 63;
    int oy0 = (tile >> 3) * 16, ox0 = (tile & 7) * 16;
    int ry0 = oy0 - 1, rx0 = ox0 - 1;
    int tid = threadIdx.x;

    const f16* Ub = U + (size_t)b * HW1;

    // stage m[ly][lx] = out129[clamp(ry0+ly), clamp(rx0+lx)]
    for (int i = tid; i < 400; i += 256) {
        int ly = i / 20, lx = i - ly * 20;
        int jy = min(max(ry0 + ly, 0), 128);
        int jx = min(max(rx0 + lx, 0), 128);
        float s = 0.f;
#pragma unroll
        for (int t = 0; t < 36; ++t) {
            int dy = t / 6, dx = t - dy * 6;
            int py = jy - 3 + dy, px = jx - 3 + dx;
            if ((unsigned)py < 128u && (unsigned)px < 128u)
                s += (float)Ub[(size_t)t * UPL + py * W1 + px];
        }
        m[ly * 21 + lx] = s;
    }
    __syncthreads();

    const float inv_scale = 129.0f / 128.0f;
    const float ksc       = 128.0f / 129.0f;

    int oy = oy0 + (tid >> 4);
    int ox = ox0 + (tid & 15);

    float sy = (oy + 0.5f) * inv_scale - 0.5f;
    float sx = (ox + 0.5f) * inv_scale - 0.5f;
    int fy = (int)floorf(sy);
    int fx = (int)floorf(sx);

    float wy[4], wx[4];
    float sumy = 0.f, sumx = 0.f;
#pragma unroll
    for (int k = 0; k < 4; ++k) {
        int jy = fy - 1 + k;
        float w = 0.f;
        if (jy >= 0 && jy < HO) w = fmaxf(0.f, 1.0f - fabsf(sy - (float)jy) * ksc);
        wy[k] = w; sumy += w;
        int jx = fx - 1 + k;
        float w2 = 0.f;
        if (jx >= 0 && jx < WO) w2 = fmaxf(0.f, 1.0f - fabsf(sx - (float)jx) * ksc);
        wx[k] = w2; sumx += w2;
    }

    float r = 0.f;
#pragma unroll
    for (int ky = 0; ky < 4; ++ky) {
        if (wy[ky] == 0.f) continue;
        int ly = fy - 1 + ky - ry0;
        float rowv = 0.f;
#pragma unroll
        for (int kx = 0; kx < 4; ++kx) {
            if (wx[kx] == 0.f) continue;
            int lx = fx - 1 + kx - rx0;
            rowv += wx[kx] * m[ly * 21 + lx];
        }
        r += wy[ky] * rowv;
    }

    out[(size_t)b * HW1 + oy * W1 + ox] = r / (sumy * sumx);
}

// ---------------------------------------------------------------------------
extern "C" void kernel_launch(void* const* d_in, const int* in_sizes, int n_in,
                              void* d_out, int out_size, void* d_ws, size_t ws_size,
                              hipStream_t stream) {
    const float* x1 = (const float*)d_in[0];   // (8,64,128,128)
    const float* x2 = (const float*)d_in[1];   // (8,64,60,60)
    float* out = (float*)d_out;

    float* ws    = (float*)d_ws;
    float* Spart = ws;                                     // 276480 floats
    float* S     = Spart + (size_t)BB * CC * NCHUNK * 36;  // 18432 floats
    f16*   U     = (f16*)(S + BB * CC * 36);               // 4.7M halves (9.4 MB)

    k_prep<<<BB * NCHUNK, 256, 0, stream>>>(x2, Spart);
    k_sum <<<72, 256, 0, stream>>>(Spart, S);
    k_gemm<<<BB * 64, 256, 0, stream>>>(x1, S, U);
    k_out <<<BB * 64, 256, 0, stream>>>(U, out);
}